// Round 2
// baseline (789.066 us; speedup 1.0000x reference)
//
#include <hip/hip_runtime.h>
#include <math.h>

#define N_ATOMS 50000
#define N_RES 6250
#define C_IN 30
#define E_DIM 12
#define E_BOND 150000
#define E_RAD 800000
#define E_RES_RAD 400000
#define E_CORR 20000

// ---------------- wave helpers ----------------
__device__ __forceinline__ float wsum(float v) {
#pragma unroll
  for (int m = 1; m < 64; m <<= 1) v += __shfl_xor(v, m, 64);
  return v;
}

// ---------------- generic row matvec: out[r][0:64] = X[r][0:K] @ W[K][64] ----------------
template <int K>
__global__ void rowmat64(const float* __restrict__ X, const float* __restrict__ W,
                         float* __restrict__ out, int nrows) {
  const int lane = threadIdx.x & 63;
  const int wid = (blockIdx.x * blockDim.x + threadIdx.x) >> 6;
  const int nw = (gridDim.x * blockDim.x) >> 6;
  float wcol[K];
#pragma unroll
  for (int k = 0; k < K; k++) wcol[k] = W[k * 64 + lane];
  for (int r = wid; r < nrows; r += nw) {
    float acc = 0.0f;
#pragma unroll
    for (int k = 0; k < K; k++) acc += X[(size_t)r * K + k] * wcol[k];
    out[(size_t)r * 64 + lane] = acc;
  }
}

// ---------------- PointConv1 edges (incl. self loops): LN(ReLU(msg@W+b)) scatter-add ----------------
__global__ void pc1_edge(const float* __restrict__ xw1, const float* __restrict__ pos,
                         const int* __restrict__ src, const int* __restrict__ dst,
                         const float* __restrict__ W, const float* __restrict__ b,
                         const float* __restrict__ g, const float* __restrict__ be,
                         float* __restrict__ acc) {
  const int lane = threadIdx.x & 63;
  const int wid = (blockIdx.x * blockDim.x + threadIdx.x) >> 6;
  const int nw = (gridDim.x * blockDim.x) >> 6;
  const float w0 = W[(C_IN + 0) * 64 + lane];
  const float w1 = W[(C_IN + 1) * 64 + lane];
  const float w2 = W[(C_IN + 2) * 64 + lane];
  const float bb = b[lane], gg = g[lane], eb = be[lane];
  const int total = E_RAD + N_ATOMS;
  for (int e = wid; e < total; e += nw) {
    int s, d;
    float dp0 = 0.0f, dp1 = 0.0f, dp2 = 0.0f;
    if (e < E_RAD) {
      // edge index is wave-uniform: pin to SGPRs so pos loads go scalar
      s = __builtin_amdgcn_readfirstlane(src[e]);
      d = __builtin_amdgcn_readfirstlane(dst[e]);
      dp0 = pos[s * 3 + 0] - pos[d * 3 + 0];
      dp1 = pos[s * 3 + 1] - pos[d * 3 + 1];
      dp2 = pos[s * 3 + 2] - pos[d * 3 + 2];
    } else {
      s = d = e - E_RAD;
    }
    float h = xw1[(size_t)s * 64 + lane] + bb + dp0 * w0 + dp1 * w1 + dp2 * w2;
    h = fmaxf(h, 0.0f);
    float mu = wsum(h) * (1.0f / 64.0f);
    float c = h - mu;
    float var = wsum(c * c) * (1.0f / 64.0f);
    float v = c / sqrtf(var + 1e-5f) * gg + eb;
    atomicAdd(&acc[(size_t)d * 64 + lane], v);
  }
}

// ---------------- GCN degree ----------------
__global__ void deg_init(float* __restrict__ deg) {
  int i = blockIdx.x * blockDim.x + threadIdx.x;
  if (i < N_ATOMS) deg[i] = 1.0f;  // self loop
}
__global__ void deg_count(const int* __restrict__ dst, float* __restrict__ deg) {
  int i = blockIdx.x * blockDim.x + threadIdx.x;
  if (i < E_BOND) atomicAdd(&deg[dst[i]], 1.0f);
}
__global__ void deg_inv(float* __restrict__ deg) {
  int i = blockIdx.x * blockDim.x + threadIdx.x;
  if (i < N_ATOMS) deg[i] = 1.0f / sqrtf(deg[i]);
}

// ---------------- GCN self-loop contribution: acc += xw2*dinv^2 + bias ----------------
__global__ void gcn_self(const float* __restrict__ xw2, const float* __restrict__ dinv,
                         const float* __restrict__ b, float* __restrict__ acc) {
  int i = blockIdx.x * blockDim.x + threadIdx.x;
  if (i < N_ATOMS * 64) {
    int n = i >> 6, lane = i & 63;
    float di = dinv[n];
    acc[i] += xw2[i] * di * di + b[lane];
  }
}

// ---------------- GCN edges ----------------
__global__ void gcn_edge(const float* __restrict__ xw2, const float* __restrict__ ea,
                         const int* __restrict__ src, const int* __restrict__ dst,
                         const float* __restrict__ W, const float* __restrict__ b,
                         const float* __restrict__ dinv, float* __restrict__ acc) {
  const int lane = threadIdx.x & 63;
  const int wid = (blockIdx.x * blockDim.x + threadIdx.x) >> 6;
  const int nw = (gridDim.x * blockDim.x) >> 6;
  float we[E_DIM];
#pragma unroll
  for (int k = 0; k < E_DIM; k++) we[k] = W[(C_IN + k) * 64 + lane];
  const float bb = b[lane];
  for (int e = wid; e < E_BOND; e += nw) {
    int s = __builtin_amdgcn_readfirstlane(src[e]);
    int d = __builtin_amdgcn_readfirstlane(dst[e]);
    float t = xw2[(size_t)s * 64 + lane];
#pragma unroll
    for (int k = 0; k < E_DIM; k++) t += ea[(size_t)e * E_DIM + k] * we[k];
    t = t * (dinv[s] * dinv[d]) + bb;
    atomicAdd(&acc[(size_t)d * 64 + lane], t);
  }
}

// ---------------- atom embed (64x64 matvec + LN) fused with residue pooling ----------------
__global__ void atom_embed(const float* __restrict__ acc12, const float* __restrict__ pos,
                           const int* __restrict__ resid, const float* __restrict__ W,
                           const float* __restrict__ b, const float* __restrict__ g,
                           const float* __restrict__ be, float* __restrict__ res_acc,
                           float* __restrict__ res_pacc, float* __restrict__ res_cnt) {
  const int lane = threadIdx.x & 63;
  const int wid = (blockIdx.x * blockDim.x + threadIdx.x) >> 6;
  const int nw = (gridDim.x * blockDim.x) >> 6;
  const float bb = b[lane], gg = g[lane], eb = be[lane];
  for (int r = wid; r < N_ATOMS; r += nw) {
    float vin = acc12[(size_t)r * 64 + lane];
    float acc = bb;
#pragma unroll 8
    for (int k = 0; k < 64; k++) {
      float xv = __shfl(vin, k, 64);
      acc += xv * W[k * 64 + lane];
    }
    float h = fmaxf(acc, 0.0f);
    float mu = wsum(h) * (1.0f / 64.0f);
    float c = h - mu;
    float var = wsum(c * c) * (1.0f / 64.0f);
    float v = c / sqrtf(var + 1e-5f) * gg + eb;
    int rr = resid[r];
    atomicAdd(&res_acc[(size_t)rr * 64 + lane], v);
    if (lane < 3) atomicAdd(&res_pacc[rr * 3 + lane], pos[r * 3 + lane]);
    if (lane == 3) atomicAdd(&res_cnt[rr], 1.0f);
  }
}

// ---------------- residue embed + res_pos finalize ----------------
__global__ void res_embed(const float* __restrict__ racc, const float* __restrict__ pacc,
                          const float* __restrict__ cnt, const float* __restrict__ W,
                          const float* __restrict__ b, const float* __restrict__ g,
                          const float* __restrict__ be, float* __restrict__ res_x,
                          float* __restrict__ res_pos) {
  const int lane = threadIdx.x & 63;
  const int wid = (blockIdx.x * blockDim.x + threadIdx.x) >> 6;
  const int nw = (gridDim.x * blockDim.x) >> 6;
  const float bb = b[lane], gg = g[lane], eb = be[lane];
  for (int r = wid; r < N_RES; r += nw) {
    float vin = racc[(size_t)r * 64 + lane];
    float acc = bb;
#pragma unroll 8
    for (int k = 0; k < 64; k++) {
      float xv = __shfl(vin, k, 64);
      acc += xv * W[k * 64 + lane];
    }
    float h = fmaxf(acc, 0.0f);
    float mu = wsum(h) * (1.0f / 64.0f);
    float c = h - mu;
    float var = wsum(c * c) * (1.0f / 64.0f);
    res_x[(size_t)r * 64 + lane] = c / sqrtf(var + 1e-5f) * gg + eb;
    if (lane < 3) res_pos[r * 3 + lane] = pacc[r * 3 + lane] / fmaxf(cnt[r], 1.0f);
  }
}

// ---------------- res_conv precompute: rw = res_x @ W_rc[0:64] + b_rc (128 wide) ----------------
__global__ void rc_pre(const float* __restrict__ rx, const float* __restrict__ W,
                       const float* __restrict__ b, float* __restrict__ rw) {
  const int lane = threadIdx.x & 63;
  const int wid = (blockIdx.x * blockDim.x + threadIdx.x) >> 6;
  const int nw = (gridDim.x * blockDim.x) >> 6;
  for (int r = wid; r < N_RES; r += nw) {
    float vin = rx[(size_t)r * 64 + lane];
    float a0 = b[lane], a1 = b[64 + lane];
#pragma unroll 8
    for (int k = 0; k < 64; k++) {
      float xv = __shfl(vin, k, 64);
      a0 += xv * W[k * 128 + lane];
      a1 += xv * W[k * 128 + 64 + lane];
    }
    rw[(size_t)r * 128 + lane] = a0;
    rw[(size_t)r * 128 + 64 + lane] = a1;
  }
}

// ---------------- res_conv edges (incl. self loops), 128-dim LN, scatter-add ----------------
__global__ void rc_edge(const float* __restrict__ rw, const float* __restrict__ rpos,
                        const int* __restrict__ src, const int* __restrict__ dst,
                        const float* __restrict__ W, const float* __restrict__ g,
                        const float* __restrict__ be, float* __restrict__ acc) {
  const int lane = threadIdx.x & 63;
  const int wid = (blockIdx.x * blockDim.x + threadIdx.x) >> 6;
  const int nw = (gridDim.x * blockDim.x) >> 6;
  float wa[3], wb[3];
#pragma unroll
  for (int i = 0; i < 3; i++) {
    wa[i] = W[(64 + i) * 128 + lane];
    wb[i] = W[(64 + i) * 128 + 64 + lane];
  }
  const float g0 = g[lane], g1 = g[64 + lane], e0 = be[lane], e1 = be[64 + lane];
  const int total = E_RES_RAD + N_RES;
  for (int e = wid; e < total; e += nw) {
    int s, d;
    float dp0 = 0.0f, dp1 = 0.0f, dp2 = 0.0f;
    if (e < E_RES_RAD) {
      s = __builtin_amdgcn_readfirstlane(src[e]);
      d = __builtin_amdgcn_readfirstlane(dst[e]);
      dp0 = rpos[s * 3 + 0] - rpos[d * 3 + 0];
      dp1 = rpos[s * 3 + 1] - rpos[d * 3 + 1];
      dp2 = rpos[s * 3 + 2] - rpos[d * 3 + 2];
    } else {
      s = d = e - E_RES_RAD;
    }
    float h0 = rw[(size_t)s * 128 + lane] + dp0 * wa[0] + dp1 * wa[1] + dp2 * wa[2];
    float h1 = rw[(size_t)s * 128 + 64 + lane] + dp0 * wb[0] + dp1 * wb[1] + dp2 * wb[2];
    h0 = fmaxf(h0, 0.0f);
    h1 = fmaxf(h1, 0.0f);
    float mu = wsum(h0 + h1) * (1.0f / 128.0f);
    float c0 = h0 - mu, c1 = h1 - mu;
    float var = wsum(c0 * c0 + c1 * c1) * (1.0f / 128.0f);
    float rs = 1.0f / sqrtf(var + 1e-5f);
    atomicAdd(&acc[(size_t)d * 128 + lane], c0 * rs * g0 + e0);
    atomicAdd(&acc[(size_t)d * 128 + 64 + lane], c1 * rs * g1 + e1);
  }
}

// ---------------- global residue MLP: x3 = LN(ReLU(acc @ W_rg + b)) ----------------
__global__ void rg_embed(const float* __restrict__ acc, const float* __restrict__ W,
                         const float* __restrict__ b, const float* __restrict__ g,
                         const float* __restrict__ be, float* __restrict__ x3) {
  const int lane = threadIdx.x & 63;
  const int wid = (blockIdx.x * blockDim.x + threadIdx.x) >> 6;
  const int nw = (gridDim.x * blockDim.x) >> 6;
  for (int r = wid; r < N_RES; r += nw) {
    float i0 = acc[(size_t)r * 128 + lane];
    float i1 = acc[(size_t)r * 128 + 64 + lane];
    float a0 = b[lane], a1 = b[64 + lane];
#pragma unroll 8
    for (int k = 0; k < 64; k++) {
      float x0 = __shfl(i0, k, 64);
      float x1 = __shfl(i1, k, 64);
      a0 += x0 * W[k * 128 + lane] + x1 * W[(k + 64) * 128 + lane];
      a1 += x0 * W[k * 128 + 64 + lane] + x1 * W[(k + 64) * 128 + 64 + lane];
    }
    float h0 = fmaxf(a0, 0.0f), h1 = fmaxf(a1, 0.0f);
    float mu = wsum(h0 + h1) * (1.0f / 128.0f);
    float c0 = h0 - mu, c1 = h1 - mu;
    float var = wsum(c0 * c0 + c1 * c1) * (1.0f / 128.0f);
    float rs = 1.0f / sqrtf(var + 1e-5f);
    x3[(size_t)r * 128 + lane] = c0 * rs * g[lane] + be[lane];
    x3[(size_t)r * 128 + 64 + lane] = c1 * rs * g[64 + lane] + be[64 + lane];
  }
}

// ---------------- cosine embedding loss partials ----------------
__global__ void loss_pairs(const float* __restrict__ x3, const int* __restrict__ si,
                           const int* __restrict__ ti, const int* __restrict__ y,
                           float* __restrict__ lacc) {
  const int lane = threadIdx.x & 63;
  const int wid = (blockIdx.x * blockDim.x + threadIdx.x) >> 6;
  const int nw = (gridDim.x * blockDim.x) >> 6;
  float sp = 0.0f, sn = 0.0f, cp = 0.0f, cn = 0.0f;
  for (int p = wid; p < E_CORR; p += nw) {
    int a = si[p], bI = ti[p], yy = y[p];
    float a0 = x3[(size_t)a * 128 + lane], a1 = x3[(size_t)a * 128 + 64 + lane];
    float b0 = x3[(size_t)bI * 128 + lane], b1 = x3[(size_t)bI * 128 + 64 + lane];
    float dot = wsum(a0 * b0 + a1 * b1);
    float na = wsum(a0 * a0 + a1 * a1);
    float nb = wsum(b0 * b0 + b1 * b1);
    float cosv = dot / (fmaxf(sqrtf(na), 1e-8f) * fmaxf(sqrtf(nb), 1e-8f));
    if (yy == 1) {
      sp += 1.0f - cosv;
      cp += 1.0f;
    } else {
      sn += fmaxf(cosv, 0.0f);
      cn += 1.0f;
    }
  }
  if (lane == 0) {
    atomicAdd(&lacc[0], sp);
    atomicAdd(&lacc[1], sn);
    atomicAdd(&lacc[2], cp);
    atomicAdd(&lacc[3], cn);
  }
}

__global__ void finalize(const float* __restrict__ lacc, float* __restrict__ out) {
  if (blockIdx.x == 0 && threadIdx.x == 0) {
    float pw = lacc[3] / lacc[2];  // neg_count / pos_count
    out[0] = (lacc[0] * pw + lacc[1]) / (float)E_CORR;
  }
}

// ---------------- launcher ----------------
extern "C" void kernel_launch(void* const* d_in, const int* in_sizes, int n_in,
                              void* d_out, int out_size, void* d_ws, size_t ws_size,
                              hipStream_t stream) {
  const float* x = (const float*)d_in[0];
  const float* pos = (const float*)d_in[1];
  const float* edge_attr = (const float*)d_in[2];
  const int* edge_index = (const int*)d_in[3];       // [2][E_BOND]
  const int* rad_ei = (const int*)d_in[4];           // [2][E_RAD]
  const int* res_rad_ei = (const int*)d_in[5];       // [2][E_RES_RAD]
  const int* resid = (const int*)d_in[6];
  const int* src_idx = (const int*)d_in[7];
  const int* tgt_idx = (const int*)d_in[8];
  const int* y_lab = (const int*)d_in[9];
  const float* w_pc1 = (const float*)d_in[10];
  const float* b_pc1 = (const float*)d_in[11];
  const float* g_pc1 = (const float*)d_in[12];
  const float* be_pc1 = (const float*)d_in[13];
  const float* w_gcn = (const float*)d_in[14];
  const float* b_gcn = (const float*)d_in[15];
  const float* w_ae = (const float*)d_in[16];
  const float* b_ae = (const float*)d_in[17];
  const float* g_ae = (const float*)d_in[18];
  const float* be_ae = (const float*)d_in[19];
  const float* w_re = (const float*)d_in[20];
  const float* b_re = (const float*)d_in[21];
  const float* g_re = (const float*)d_in[22];
  const float* be_re = (const float*)d_in[23];
  const float* w_rc = (const float*)d_in[24];
  const float* b_rc = (const float*)d_in[25];
  const float* g_rc = (const float*)d_in[26];
  const float* be_rc = (const float*)d_in[27];
  const float* w_rg = (const float*)d_in[28];
  const float* b_rg = (const float*)d_in[29];
  const float* g_rg = (const float*)d_in[30];
  const float* be_rg = (const float*)d_in[31];

  float* ws = (float*)d_ws;
  // zeroed region (single memset)
  float* acc12 = ws;                              // N_ATOMS*64   = 3,200,000
  float* res_acc = acc12 + (size_t)N_ATOMS * 64;  // N_RES*64  = 400,000
  float* res_pacc = res_acc + (size_t)N_RES * 64; // N_RES*3 (pad) = 18752
  float* res_cnt = res_pacc + 18752;              // N_RES (pad)  = 6272
  float* x3acc = res_cnt + 6272;                  // N_RES*128    = 800,000
  float* lacc = x3acc + (size_t)N_RES * 128;      // 8
  size_t zero_floats = (size_t)N_ATOMS * 64 + (size_t)N_RES * 64 + 18752 + 6272 +
                       (size_t)N_RES * 128 + 8;
  // non-zeroed region
  float* xw1 = lacc + 8;                          // N_ATOMS*64
  float* xw2 = xw1 + (size_t)N_ATOMS * 64;        // N_ATOMS*64
  float* deg = xw2 + (size_t)N_ATOMS * 64;        // N_ATOMS
  float* res_x = deg + N_ATOMS;                   // N_RES*64
  float* res_pos = res_x + (size_t)N_RES * 64;    // N_RES*3 (pad)
  float* rw = res_pos + 18752;                    // N_RES*128
  float* x3 = rw + (size_t)N_RES * 128;           // N_RES*128

  hipMemsetAsync(d_ws, 0, zero_floats * sizeof(float), stream);

  const int B = 256;
  const int GB = 2048;  // big grids (8 blocks/CU x 256 CU)
  const int GS = 512;   // residue-level grids

  // PointConv1
  rowmat64<C_IN><<<GB, B, 0, stream>>>(x, w_pc1, xw1, N_ATOMS);
  pc1_edge<<<GB, B, 0, stream>>>(xw1, pos, rad_ei, rad_ei + E_RAD, w_pc1, b_pc1, g_pc1,
                                 be_pc1, acc12);

  // GCN degree + norm
  deg_init<<<(N_ATOMS + B - 1) / B, B, 0, stream>>>(deg);
  deg_count<<<(E_BOND + B - 1) / B, B, 0, stream>>>(edge_index + E_BOND, deg);
  deg_inv<<<(N_ATOMS + B - 1) / B, B, 0, stream>>>(deg);

  // GCN
  rowmat64<C_IN><<<GB, B, 0, stream>>>(x, w_gcn, xw2, N_ATOMS);
  gcn_self<<<(N_ATOMS * 64 + B - 1) / B, B, 0, stream>>>(xw2, deg, b_gcn, acc12);
  gcn_edge<<<GB, B, 0, stream>>>(xw2, edge_attr, edge_index, edge_index + E_BOND, w_gcn,
                                 b_gcn, deg, acc12);

  // atom embed + pooling
  atom_embed<<<GB, B, 0, stream>>>(acc12, pos, resid, w_ae, b_ae, g_ae, be_ae, res_acc,
                                   res_pacc, res_cnt);

  // residue embed
  res_embed<<<GS, B, 0, stream>>>(res_acc, res_pacc, res_cnt, w_re, b_re, g_re, be_re,
                                  res_x, res_pos);

  // residue PointConv
  rc_pre<<<GS, B, 0, stream>>>(res_x, w_rc, b_rc, rw);
  rc_edge<<<GB, B, 0, stream>>>(rw, res_pos, res_rad_ei, res_rad_ei + E_RES_RAD, w_rc,
                                g_rc, be_rc, x3acc);
  rg_embed<<<GS, B, 0, stream>>>(x3acc, w_rg, b_rg, g_rg, be_rg, x3);

  // loss
  loss_pairs<<<GS, B, 0, stream>>>(x3, src_idx, tgt_idx, y_lab, lacc);
  finalize<<<1, 64, 0, stream>>>(lacc, (float*)d_out);
}

// Round 3
// 772.933 us; speedup vs baseline: 1.0209x; 1.0209x over previous
//
#include <hip/hip_runtime.h>
#include <math.h>

#define N_ATOMS 50000
#define N_RES 6250
#define C_IN 30
#define E_DIM 12
#define E_BOND 150000
#define E_RAD 800000
#define E_RES_RAD 400000
#define E_CORR 20000

__device__ __forceinline__ int rfl(int v) { return __builtin_amdgcn_readfirstlane(v); }

__device__ __forceinline__ float wsum(float v) {
#pragma unroll
  for (int m = 1; m < 64; m <<= 1) v += __shfl_xor(v, m, 64);
  return v;
}

// ---------------- generic row matvec: out[r][0:64] = X[r][0:K] @ W[K][64] ----------------
template <int K>
__global__ void rowmat64(const float* __restrict__ X, const float* __restrict__ W,
                         float* __restrict__ out, int nrows) {
  const int lane = threadIdx.x & 63;
  const int wid = (blockIdx.x * blockDim.x + threadIdx.x) >> 6;
  const int nw = (gridDim.x * blockDim.x) >> 6;
  float wcol[K];
#pragma unroll
  for (int k = 0; k < K; k++) wcol[k] = W[k * 64 + lane];
  for (int r = wid; r < nrows; r += nw) {
    float acc = 0.0f;
#pragma unroll
    for (int k = 0; k < K; k++) acc += X[(size_t)r * K + k] * wcol[k];
    out[(size_t)r * 64 + lane] = acc;
  }
}

// ---------------- PointConv1 edges, ILP-2, one-pass LN ----------------
// total = E_RAD + N_ATOMS is even, grid-stride by 2 -> no tail guard needed
__global__ void pc1_edge(const float* __restrict__ xw1, const float* __restrict__ pos,
                         const int* __restrict__ src, const int* __restrict__ dst,
                         const float* __restrict__ W, const float* __restrict__ b,
                         const float* __restrict__ g, const float* __restrict__ be,
                         float* __restrict__ acc) {
  const int lane = threadIdx.x & 63;
  const int wid = (blockIdx.x * blockDim.x + threadIdx.x) >> 6;
  const int nw = (gridDim.x * blockDim.x) >> 6;
  const float w0 = W[(C_IN + 0) * 64 + lane];
  const float w1 = W[(C_IN + 1) * 64 + lane];
  const float w2 = W[(C_IN + 2) * 64 + lane];
  const float bb = b[lane], gg = g[lane], eb = be[lane];
  const int total = E_RAD + N_ATOMS;
  for (int e0 = wid * 2; e0 < total; e0 += nw * 2) {
    const int e1 = e0 + 1;
    // ---- gather phase (both edges) ----
    int sA, dA, sB, dB;
    float dA0 = 0.0f, dA1 = 0.0f, dA2 = 0.0f, dB0 = 0.0f, dB1 = 0.0f, dB2 = 0.0f;
    if (e0 < E_RAD) {
      sA = rfl(src[e0]); dA = rfl(dst[e0]);
      dA0 = pos[sA * 3 + 0] - pos[dA * 3 + 0];
      dA1 = pos[sA * 3 + 1] - pos[dA * 3 + 1];
      dA2 = pos[sA * 3 + 2] - pos[dA * 3 + 2];
    } else {
      sA = dA = e0 - E_RAD;
    }
    if (e1 < E_RAD) {
      sB = rfl(src[e1]); dB = rfl(dst[e1]);
      dB0 = pos[sB * 3 + 0] - pos[dB * 3 + 0];
      dB1 = pos[sB * 3 + 1] - pos[dB * 3 + 1];
      dB2 = pos[sB * 3 + 2] - pos[dB * 3 + 2];
    } else {
      sB = dB = e1 - E_RAD;
    }
    float hA = xw1[(size_t)sA * 64 + lane] + bb + dA0 * w0 + dA1 * w1 + dA2 * w2;
    float hB = xw1[(size_t)sB * 64 + lane] + bb + dB0 * w0 + dB1 * w1 + dB2 * w2;
    hA = fmaxf(hA, 0.0f);
    hB = fmaxf(hB, 0.0f);
    // ---- dual one-pass LN: 4 independent butterfly chains ----
    float s1A = hA, s2A = hA * hA, s1B = hB, s2B = hB * hB;
#pragma unroll
    for (int m = 1; m < 64; m <<= 1) {
      s1A += __shfl_xor(s1A, m, 64);
      s2A += __shfl_xor(s2A, m, 64);
      s1B += __shfl_xor(s1B, m, 64);
      s2B += __shfl_xor(s2B, m, 64);
    }
    const float muA = s1A * (1.0f / 64.0f);
    const float muB = s1B * (1.0f / 64.0f);
    const float vaA = s2A * (1.0f / 64.0f) - muA * muA;
    const float vaB = s2B * (1.0f / 64.0f) - muB * muB;
    const float rA = rsqrtf(vaA + 1e-5f);
    const float rB = rsqrtf(vaB + 1e-5f);
    atomicAdd(&acc[(size_t)dA * 64 + lane], (hA - muA) * rA * gg + eb);
    atomicAdd(&acc[(size_t)dB * 64 + lane], (hB - muB) * rB * gg + eb);
  }
}

// ---------------- GCN degree ----------------
__global__ void deg_init(float* __restrict__ deg) {
  int i = blockIdx.x * blockDim.x + threadIdx.x;
  if (i < N_ATOMS) deg[i] = 1.0f;  // self loop
}
__global__ void deg_count(const int* __restrict__ dst, float* __restrict__ deg) {
  int i = blockIdx.x * blockDim.x + threadIdx.x;
  if (i < E_BOND) atomicAdd(&deg[dst[i]], 1.0f);
}
__global__ void deg_inv(float* __restrict__ deg) {
  int i = blockIdx.x * blockDim.x + threadIdx.x;
  if (i < N_ATOMS) deg[i] = rsqrtf(deg[i]);
}

// ---------------- GCN edges ----------------
__global__ void gcn_edge(const float* __restrict__ xw2, const float* __restrict__ ea,
                         const int* __restrict__ src, const int* __restrict__ dst,
                         const float* __restrict__ W, const float* __restrict__ b,
                         const float* __restrict__ dinv, float* __restrict__ acc) {
  const int lane = threadIdx.x & 63;
  const int wid = (blockIdx.x * blockDim.x + threadIdx.x) >> 6;
  const int nw = (gridDim.x * blockDim.x) >> 6;
  float we[E_DIM];
#pragma unroll
  for (int k = 0; k < E_DIM; k++) we[k] = W[(C_IN + k) * 64 + lane];
  const float bb = b[lane];
  for (int e = wid; e < E_BOND; e += nw) {
    int s = rfl(src[e]);
    int d = rfl(dst[e]);
    float t = xw2[(size_t)s * 64 + lane];
#pragma unroll
    for (int k = 0; k < E_DIM; k++) t += ea[(size_t)e * E_DIM + k] * we[k];
    t = t * (dinv[s] * dinv[d]) + bb;
    atomicAdd(&acc[(size_t)d * 64 + lane], t);
  }
}

// ---------------- atom embed (fused with GCN self-loop term) + residue pooling ----------------
__global__ void atom_embed(const float* __restrict__ acc12, const float* __restrict__ xw2,
                           const float* __restrict__ dinv, const float* __restrict__ bgcn,
                           const float* __restrict__ pos, const int* __restrict__ resid,
                           const float* __restrict__ W, const float* __restrict__ b,
                           const float* __restrict__ g, const float* __restrict__ be,
                           float* __restrict__ res_acc, float* __restrict__ res_pacc,
                           float* __restrict__ res_cnt) {
  const int lane = threadIdx.x & 63;
  const int wid = (blockIdx.x * blockDim.x + threadIdx.x) >> 6;
  const int nw = (gridDim.x * blockDim.x) >> 6;
  const float bb = b[lane], gg = g[lane], eb = be[lane], bg = bgcn[lane];
  for (int r = wid; r < N_ATOMS; r += nw) {
    const float di = dinv[r];
    float vin = acc12[(size_t)r * 64 + lane] + xw2[(size_t)r * 64 + lane] * di * di + bg;
    float acc = bb;
#pragma unroll 8
    for (int k = 0; k < 64; k++) {
      float xv = __shfl(vin, k, 64);
      acc += xv * W[k * 64 + lane];
    }
    float h = fmaxf(acc, 0.0f);
    float s1 = h, s2 = h * h;
#pragma unroll
    for (int m = 1; m < 64; m <<= 1) {
      s1 += __shfl_xor(s1, m, 64);
      s2 += __shfl_xor(s2, m, 64);
    }
    float mu = s1 * (1.0f / 64.0f);
    float var = s2 * (1.0f / 64.0f) - mu * mu;
    float v = (h - mu) * rsqrtf(var + 1e-5f) * gg + eb;
    int rr = resid[r];
    atomicAdd(&res_acc[(size_t)rr * 64 + lane], v);
    if (lane < 3) atomicAdd(&res_pacc[rr * 3 + lane], pos[r * 3 + lane]);
    if (lane == 3) atomicAdd(&res_cnt[rr], 1.0f);
  }
}

// ---------------- residue embed + res_pos finalize ----------------
__global__ void res_embed(const float* __restrict__ racc, const float* __restrict__ pacc,
                          const float* __restrict__ cnt, const float* __restrict__ W,
                          const float* __restrict__ b, const float* __restrict__ g,
                          const float* __restrict__ be, float* __restrict__ res_x,
                          float* __restrict__ res_pos) {
  const int lane = threadIdx.x & 63;
  const int wid = (blockIdx.x * blockDim.x + threadIdx.x) >> 6;
  const int nw = (gridDim.x * blockDim.x) >> 6;
  const float bb = b[lane], gg = g[lane], eb = be[lane];
  for (int r = wid; r < N_RES; r += nw) {
    float vin = racc[(size_t)r * 64 + lane];
    float acc = bb;
#pragma unroll 8
    for (int k = 0; k < 64; k++) {
      float xv = __shfl(vin, k, 64);
      acc += xv * W[k * 64 + lane];
    }
    float h = fmaxf(acc, 0.0f);
    float s1 = h, s2 = h * h;
#pragma unroll
    for (int m = 1; m < 64; m <<= 1) {
      s1 += __shfl_xor(s1, m, 64);
      s2 += __shfl_xor(s2, m, 64);
    }
    float mu = s1 * (1.0f / 64.0f);
    float var = s2 * (1.0f / 64.0f) - mu * mu;
    res_x[(size_t)r * 64 + lane] = (h - mu) * rsqrtf(var + 1e-5f) * gg + eb;
    if (lane < 3) res_pos[r * 3 + lane] = pacc[r * 3 + lane] / fmaxf(cnt[r], 1.0f);
  }
}

// ---------------- res_conv precompute: rw = res_x @ W_rc[0:64] + b_rc (128 wide) ----------------
__global__ void rc_pre(const float* __restrict__ rx, const float* __restrict__ W,
                       const float* __restrict__ b, float* __restrict__ rw) {
  const int lane = threadIdx.x & 63;
  const int wid = (blockIdx.x * blockDim.x + threadIdx.x) >> 6;
  const int nw = (gridDim.x * blockDim.x) >> 6;
  for (int r = wid; r < N_RES; r += nw) {
    float vin = rx[(size_t)r * 64 + lane];
    float a0 = b[lane], a1 = b[64 + lane];
#pragma unroll 8
    for (int k = 0; k < 64; k++) {
      float xv = __shfl(vin, k, 64);
      a0 += xv * W[k * 128 + lane];
      a1 += xv * W[k * 128 + 64 + lane];
    }
    rw[(size_t)r * 128 + lane] = a0;
    rw[(size_t)r * 128 + 64 + lane] = a1;
  }
}

// ---------------- res_conv edges, ILP-2, one-pass LN over 128 dims ----------------
// total = E_RES_RAD + N_RES is even
__global__ void rc_edge(const float* __restrict__ rw, const float* __restrict__ rpos,
                        const int* __restrict__ src, const int* __restrict__ dst,
                        const float* __restrict__ W, const float* __restrict__ g,
                        const float* __restrict__ be, float* __restrict__ acc) {
  const int lane = threadIdx.x & 63;
  const int wid = (blockIdx.x * blockDim.x + threadIdx.x) >> 6;
  const int nw = (gridDim.x * blockDim.x) >> 6;
  float wa[3], wb[3];
#pragma unroll
  for (int i = 0; i < 3; i++) {
    wa[i] = W[(64 + i) * 128 + lane];
    wb[i] = W[(64 + i) * 128 + 64 + lane];
  }
  const float g0 = g[lane], g1 = g[64 + lane], e0c = be[lane], e1c = be[64 + lane];
  const int total = E_RES_RAD + N_RES;
  for (int e0 = wid * 2; e0 < total; e0 += nw * 2) {
    const int e1 = e0 + 1;
    int sA, dA, sB, dB;
    float dA0 = 0.0f, dA1 = 0.0f, dA2 = 0.0f, dB0 = 0.0f, dB1 = 0.0f, dB2 = 0.0f;
    if (e0 < E_RES_RAD) {
      sA = rfl(src[e0]); dA = rfl(dst[e0]);
      dA0 = rpos[sA * 3 + 0] - rpos[dA * 3 + 0];
      dA1 = rpos[sA * 3 + 1] - rpos[dA * 3 + 1];
      dA2 = rpos[sA * 3 + 2] - rpos[dA * 3 + 2];
    } else {
      sA = dA = e0 - E_RES_RAD;
    }
    if (e1 < E_RES_RAD) {
      sB = rfl(src[e1]); dB = rfl(dst[e1]);
      dB0 = rpos[sB * 3 + 0] - rpos[dB * 3 + 0];
      dB1 = rpos[sB * 3 + 1] - rpos[dB * 3 + 1];
      dB2 = rpos[sB * 3 + 2] - rpos[dB * 3 + 2];
    } else {
      sB = dB = e1 - E_RES_RAD;
    }
    float hA0 = rw[(size_t)sA * 128 + lane]      + dA0 * wa[0] + dA1 * wa[1] + dA2 * wa[2];
    float hA1 = rw[(size_t)sA * 128 + 64 + lane] + dA0 * wb[0] + dA1 * wb[1] + dA2 * wb[2];
    float hB0 = rw[(size_t)sB * 128 + lane]      + dB0 * wa[0] + dB1 * wa[1] + dB2 * wa[2];
    float hB1 = rw[(size_t)sB * 128 + 64 + lane] + dB0 * wb[0] + dB1 * wb[1] + dB2 * wb[2];
    hA0 = fmaxf(hA0, 0.0f); hA1 = fmaxf(hA1, 0.0f);
    hB0 = fmaxf(hB0, 0.0f); hB1 = fmaxf(hB1, 0.0f);
    float s1A = hA0 + hA1, s2A = hA0 * hA0 + hA1 * hA1;
    float s1B = hB0 + hB1, s2B = hB0 * hB0 + hB1 * hB1;
#pragma unroll
    for (int m = 1; m < 64; m <<= 1) {
      s1A += __shfl_xor(s1A, m, 64);
      s2A += __shfl_xor(s2A, m, 64);
      s1B += __shfl_xor(s1B, m, 64);
      s2B += __shfl_xor(s2B, m, 64);
    }
    const float muA = s1A * (1.0f / 128.0f);
    const float muB = s1B * (1.0f / 128.0f);
    const float vaA = s2A * (1.0f / 128.0f) - muA * muA;
    const float vaB = s2B * (1.0f / 128.0f) - muB * muB;
    const float rsA = rsqrtf(vaA + 1e-5f);
    const float rsB = rsqrtf(vaB + 1e-5f);
    atomicAdd(&acc[(size_t)dA * 128 + lane],      (hA0 - muA) * rsA * g0 + e0c);
    atomicAdd(&acc[(size_t)dA * 128 + 64 + lane], (hA1 - muA) * rsA * g1 + e1c);
    atomicAdd(&acc[(size_t)dB * 128 + lane],      (hB0 - muB) * rsB * g0 + e0c);
    atomicAdd(&acc[(size_t)dB * 128 + 64 + lane], (hB1 - muB) * rsB * g1 + e1c);
  }
}

// ---------------- global residue MLP: x3 = LN(ReLU(acc @ W_rg + b)) ----------------
__global__ void rg_embed(const float* __restrict__ acc, const float* __restrict__ W,
                         const float* __restrict__ b, const float* __restrict__ g,
                         const float* __restrict__ be, float* __restrict__ x3) {
  const int lane = threadIdx.x & 63;
  const int wid = (blockIdx.x * blockDim.x + threadIdx.x) >> 6;
  const int nw = (gridDim.x * blockDim.x) >> 6;
  for (int r = wid; r < N_RES; r += nw) {
    float i0 = acc[(size_t)r * 128 + lane];
    float i1 = acc[(size_t)r * 128 + 64 + lane];
    float a0 = b[lane], a1 = b[64 + lane];
#pragma unroll 8
    for (int k = 0; k < 64; k++) {
      float x0 = __shfl(i0, k, 64);
      float x1 = __shfl(i1, k, 64);
      a0 += x0 * W[k * 128 + lane] + x1 * W[(k + 64) * 128 + lane];
      a1 += x0 * W[k * 128 + 64 + lane] + x1 * W[(k + 64) * 128 + 64 + lane];
    }
    float h0 = fmaxf(a0, 0.0f), h1 = fmaxf(a1, 0.0f);
    float s1 = h0 + h1, s2 = h0 * h0 + h1 * h1;
#pragma unroll
    for (int m = 1; m < 64; m <<= 1) {
      s1 += __shfl_xor(s1, m, 64);
      s2 += __shfl_xor(s2, m, 64);
    }
    float mu = s1 * (1.0f / 128.0f);
    float var = s2 * (1.0f / 128.0f) - mu * mu;
    float rs = rsqrtf(var + 1e-5f);
    x3[(size_t)r * 128 + lane] = (h0 - mu) * rs * g[lane] + be[lane];
    x3[(size_t)r * 128 + 64 + lane] = (h1 - mu) * rs * g[64 + lane] + be[64 + lane];
  }
}

// ---------------- cosine embedding loss partials ----------------
__global__ void loss_pairs(const float* __restrict__ x3, const int* __restrict__ si,
                           const int* __restrict__ ti, const int* __restrict__ y,
                           float* __restrict__ lacc) {
  const int lane = threadIdx.x & 63;
  const int wid = (blockIdx.x * blockDim.x + threadIdx.x) >> 6;
  const int nw = (gridDim.x * blockDim.x) >> 6;
  float sp = 0.0f, sn = 0.0f, cp = 0.0f, cn = 0.0f;
  for (int p = wid; p < E_CORR; p += nw) {
    int a = rfl(si[p]), bI = rfl(ti[p]), yy = rfl(y[p]);
    float a0 = x3[(size_t)a * 128 + lane], a1 = x3[(size_t)a * 128 + 64 + lane];
    float b0 = x3[(size_t)bI * 128 + lane], b1 = x3[(size_t)bI * 128 + 64 + lane];
    float dot = a0 * b0 + a1 * b1;
    float na = a0 * a0 + a1 * a1;
    float nb = b0 * b0 + b1 * b1;
#pragma unroll
    for (int m = 1; m < 64; m <<= 1) {
      dot += __shfl_xor(dot, m, 64);
      na += __shfl_xor(na, m, 64);
      nb += __shfl_xor(nb, m, 64);
    }
    float cosv = dot / (fmaxf(sqrtf(na), 1e-8f) * fmaxf(sqrtf(nb), 1e-8f));
    if (yy == 1) {
      sp += 1.0f - cosv;
      cp += 1.0f;
    } else {
      sn += fmaxf(cosv, 0.0f);
      cn += 1.0f;
    }
  }
  if (lane == 0) {
    atomicAdd(&lacc[0], sp);
    atomicAdd(&lacc[1], sn);
    atomicAdd(&lacc[2], cp);
    atomicAdd(&lacc[3], cn);
  }
}

__global__ void finalize(const float* __restrict__ lacc, float* __restrict__ out) {
  if (blockIdx.x == 0 && threadIdx.x == 0) {
    float pw = lacc[3] / lacc[2];  // neg_count / pos_count
    out[0] = (lacc[0] * pw + lacc[1]) / (float)E_CORR;
  }
}

// ---------------- launcher ----------------
extern "C" void kernel_launch(void* const* d_in, const int* in_sizes, int n_in,
                              void* d_out, int out_size, void* d_ws, size_t ws_size,
                              hipStream_t stream) {
  const float* x = (const float*)d_in[0];
  const float* pos = (const float*)d_in[1];
  const float* edge_attr = (const float*)d_in[2];
  const int* edge_index = (const int*)d_in[3];       // [2][E_BOND]
  const int* rad_ei = (const int*)d_in[4];           // [2][E_RAD]
  const int* res_rad_ei = (const int*)d_in[5];       // [2][E_RES_RAD]
  const int* resid = (const int*)d_in[6];
  const int* src_idx = (const int*)d_in[7];
  const int* tgt_idx = (const int*)d_in[8];
  const int* y_lab = (const int*)d_in[9];
  const float* w_pc1 = (const float*)d_in[10];
  const float* b_pc1 = (const float*)d_in[11];
  const float* g_pc1 = (const float*)d_in[12];
  const float* be_pc1 = (const float*)d_in[13];
  const float* w_gcn = (const float*)d_in[14];
  const float* b_gcn = (const float*)d_in[15];
  const float* w_ae = (const float*)d_in[16];
  const float* b_ae = (const float*)d_in[17];
  const float* g_ae = (const float*)d_in[18];
  const float* be_ae = (const float*)d_in[19];
  const float* w_re = (const float*)d_in[20];
  const float* b_re = (const float*)d_in[21];
  const float* g_re = (const float*)d_in[22];
  const float* be_re = (const float*)d_in[23];
  const float* w_rc = (const float*)d_in[24];
  const float* b_rc = (const float*)d_in[25];
  const float* g_rc = (const float*)d_in[26];
  const float* be_rc = (const float*)d_in[27];
  const float* w_rg = (const float*)d_in[28];
  const float* b_rg = (const float*)d_in[29];
  const float* g_rg = (const float*)d_in[30];
  const float* be_rg = (const float*)d_in[31];

  float* ws = (float*)d_ws;
  // zeroed region (single memset)
  float* acc12 = ws;                              // N_ATOMS*64   = 3,200,000
  float* res_acc = acc12 + (size_t)N_ATOMS * 64;  // N_RES*64  = 400,000
  float* res_pacc = res_acc + (size_t)N_RES * 64; // N_RES*3 (pad) = 18752
  float* res_cnt = res_pacc + 18752;              // N_RES (pad)  = 6272
  float* x3acc = res_cnt + 6272;                  // N_RES*128    = 800,000
  float* lacc = x3acc + (size_t)N_RES * 128;      // 8
  size_t zero_floats = (size_t)N_ATOMS * 64 + (size_t)N_RES * 64 + 18752 + 6272 +
                       (size_t)N_RES * 128 + 8;
  // non-zeroed region
  float* xw1 = lacc + 8;                          // N_ATOMS*64
  float* xw2 = xw1 + (size_t)N_ATOMS * 64;        // N_ATOMS*64
  float* deg = xw2 + (size_t)N_ATOMS * 64;        // N_ATOMS
  float* res_x = deg + N_ATOMS;                   // N_RES*64
  float* res_pos = res_x + (size_t)N_RES * 64;    // N_RES*3 (pad)
  float* rw = res_pos + 18752;                    // N_RES*128
  float* x3 = rw + (size_t)N_RES * 128;           // N_RES*128

  hipMemsetAsync(d_ws, 0, zero_floats * sizeof(float), stream);

  const int B = 256;
  const int GB = 2048;  // big grids (8 blocks/CU x 256 CU)
  const int GS = 512;   // residue-level grids

  // PointConv1
  rowmat64<C_IN><<<GB, B, 0, stream>>>(x, w_pc1, xw1, N_ATOMS);
  pc1_edge<<<GB, B, 0, stream>>>(xw1, pos, rad_ei, rad_ei + E_RAD, w_pc1, b_pc1, g_pc1,
                                 be_pc1, acc12);

  // GCN degree + norm
  deg_init<<<(N_ATOMS + B - 1) / B, B, 0, stream>>>(deg);
  deg_count<<<(E_BOND + B - 1) / B, B, 0, stream>>>(edge_index + E_BOND, deg);
  deg_inv<<<(N_ATOMS + B - 1) / B, B, 0, stream>>>(deg);

  // GCN (self-loop term is fused into atom_embed)
  rowmat64<C_IN><<<GB, B, 0, stream>>>(x, w_gcn, xw2, N_ATOMS);
  gcn_edge<<<GB, B, 0, stream>>>(xw2, edge_attr, edge_index, edge_index + E_BOND, w_gcn,
                                 b_gcn, deg, acc12);

  // atom embed + pooling (+= xw2*dinv^2 + b_gcn fused)
  atom_embed<<<GB, B, 0, stream>>>(acc12, xw2, deg, b_gcn, pos, resid, w_ae, b_ae, g_ae,
                                   be_ae, res_acc, res_pacc, res_cnt);

  // residue embed
  res_embed<<<GS, B, 0, stream>>>(res_acc, res_pacc, res_cnt, w_re, b_re, g_re, be_re,
                                  res_x, res_pos);

  // residue PointConv
  rc_pre<<<GS, B, 0, stream>>>(res_x, w_rc, b_rc, rw);
  rc_edge<<<GB, B, 0, stream>>>(rw, res_pos, res_rad_ei, res_rad_ei + E_RES_RAD, w_rc,
                                g_rc, be_rc, x3acc);
  rg_embed<<<GS, B, 0, stream>>>(x3acc, w_rg, b_rg, g_rg, be_rg, x3);

  // loss
  loss_pairs<<<GS, B, 0, stream>>>(x3, src_idx, tgt_idx, y_lab, lacc);
  finalize<<<1, 64, 0, stream>>>(lacc, (float*)d_out);
}